// Round 1
// baseline (10409.144 us; speedup 1.0000x reference)
//
#include <hip/hip_runtime.h>

// MultiScalePointNet fused fp32 baseline.
// N=100000 points, K=20 neighbors, scales {5,10,20}, D=256.
// One kernel; block=256 threads handles TPTS=8 points end-to-end.
// Compute-bound: 168 G MAC fp32. Weights stream from L1/L2 (float4),
// activations broadcast from LDS. No workspace needed.

#define TPTS 8
#define KMAX 20

__device__ __forceinline__ float leaky(float x) { return fmaxf(x, 0.2f * x); }

struct Params {
    const float* points;   // [N,3]
    const int*   nidx;     // [N,20] (harness passes integer inputs as int32)
    const float* pw1; const float* pb1;   // [3,64,3], [3,64]
    const float* pw2; const float* pb2;   // [3,128,64], [3,128]
    const float* pw3; const float* pb3;   // [3,256,128], [3,256]
    const float* sw1; const float* sb1;   // [256,768], [256]
    const float* sw2; const float* sb2;   // [128,256], [128]
    const float* sw3; const float* sb3;   // [64,128], [64]
    const float* sw4; const float* sb4;   // [32,64], [32]
    const float* sw5; const float* sb5;   // [1,32], [1]
    float* out;            // [N]
    int n;
};

// LDS pool layout (floats):
//   sx  : [8][768]  offset 0      (6144)
//   regA: 4096      offset 6144   (patch scratch: idx/nb/h1/h2; later hs1[8][256], hs3[8][64])
//   regB: 1024      offset 10240  (hs2[8][128], hs4[8][32])
#define POOL_FLOATS (6144 + 4096 + 1024)

template <int S>
__device__ void process_scale(int i, const Params& p, float* sxrow,
                              float* sh1, float* sh2, const float* snb, int tid) {
    // ---- L1: [S,3] -> [S,64], leaky ----
    for (int o = tid; o < S * 64; o += 256) {
        int k = o >> 6, d = o & 63;
        const float* wr = p.pw1 + (i * 64 + d) * 3;
        float acc = p.pb1[i * 64 + d]
                  + snb[k * 3 + 0] * wr[0]
                  + snb[k * 3 + 1] * wr[1]
                  + snb[k * 3 + 2] * wr[2];
        sh1[k * 64 + d] = leaky(acc);
    }
    __syncthreads();
    // ---- L2: [S,64] -> [S,128], leaky ----
    for (int o = tid; o < S * 128; o += 256) {
        int k = o >> 7, d = o & 127;
        const float4* wr = (const float4*)(p.pw2 + (i * 128 + d) * 64);
        const float4* hr = (const float4*)(sh1 + k * 64);
        float a0 = 0.f, a1 = 0.f;
#pragma unroll
        for (int c = 0; c < 16; c += 2) {
            float4 w0 = wr[c],     h0 = hr[c];
            float4 w1 = wr[c + 1], h1 = hr[c + 1];
            a0 += w0.x * h0.x + w0.y * h0.y + w0.z * h0.z + w0.w * h0.w;
            a1 += w1.x * h1.x + w1.y * h1.y + w1.z * h1.z + w1.w * h1.w;
        }
        sh2[k * 128 + d] = leaky(a0 + a1 + p.pb2[i * 128 + d]);
    }
    __syncthreads();
    // ---- L3 + maxpool: [S,128] -> [S,256] -> max over S. thread d = tid ----
    {
        const float4* wr = (const float4*)(p.pw3 + (i * 256 + tid) * 128);
        float acc[S];
#pragma unroll
        for (int k = 0; k < S; k++) acc[k] = 0.f;
        for (int c = 0; c < 32; c++) {
            float4 w = wr[c];
#pragma unroll
            for (int k = 0; k < S; k++) {
                float4 h = ((const float4*)(sh2 + k * 128))[c];
                acc[k] += w.x * h.x + w.y * h.y + w.z * h.z + w.w * h.w;
            }
        }
        float m = acc[0];
#pragma unroll
        for (int k = 1; k < S; k++) m = fmaxf(m, acc[k]);
        sxrow[i * 256 + tid] = m + p.pb3[i * 256 + tid];  // bias after max == max after bias
    }
    __syncthreads();
}

__global__ __launch_bounds__(256) void msp_kernel(Params p) {
    __shared__ __align__(16) float pool[POOL_FLOATS];
    float* sx = pool;               // [8][768]
    float* rA = pool + 6144;        // 4096 floats
    float* rB = pool + 6144 + 4096; // 1024 floats
    int*   sidx = (int*)rA;         // [20]
    float* snb  = rA + 32;          // [20][3]
    float* sh1  = rA + 96;          // [20][64]  (16B-aligned)
    float* sh2  = rA + 1376;        // [20][128] (16B-aligned)

    const int tid = threadIdx.x;
    const int n0  = blockIdx.x * TPTS;

    // ---------------- patch stage: per point ----------------
    for (int pp = 0; pp < TPTS; ++pp) {
        const int n = n0 + pp;
        if (n >= p.n) break;  // uniform across block
        if (tid < KMAX) sidx[tid] = p.nidx[n * KMAX + tid];
        __syncthreads();
        if (tid < KMAX * 3) {
            int k = tid / 3, c = tid - k * 3;
            snb[k * 3 + c] = p.points[sidx[k] * 3 + c] - p.points[n * 3 + c];
        }
        __syncthreads();
        float* sxrow = sx + pp * 768;
        process_scale<5>(0, p, sxrow, sh1, sh2, snb, tid);
        process_scale<10>(1, p, sxrow, sh1, sh2, snb, tid);
        process_scale<20>(2, p, sxrow, sh1, sh2, snb, tid);
    }
    __syncthreads();

    // ---------------- shared MLP on 8 points ----------------
    // Layer 1: [8,768] -> [8,256], thread d = tid, 8 point-accumulators.
    {
        const float4* wr = (const float4*)(p.sw1 + tid * 768);
        float acc[TPTS];
#pragma unroll
        for (int q = 0; q < TPTS; q++) acc[q] = 0.f;
        for (int c = 0; c < 192; c++) {
            float4 w = wr[c];
#pragma unroll
            for (int q = 0; q < TPTS; q++) {
                float4 xv = ((const float4*)(sx + q * 768))[c];
                acc[q] += w.x * xv.x + w.y * xv.y + w.z * xv.z + w.w * xv.w;
            }
        }
        float b = p.sb1[tid];
#pragma unroll
        for (int q = 0; q < TPTS; q++) rA[q * 256 + tid] = leaky(acc[q] + b);
    }
    __syncthreads();
    // Layer 2: [8,256] -> [8,128]. d = tid&127, 4 points per thread-half.
    {
        int d = tid & 127, q0 = (tid >> 7) * 4;
        const float4* wr = (const float4*)(p.sw2 + d * 256);
        float acc[4] = {0.f, 0.f, 0.f, 0.f};
        for (int c = 0; c < 64; c++) {
            float4 w = wr[c];
#pragma unroll
            for (int q = 0; q < 4; q++) {
                float4 h = ((const float4*)(rA + (q0 + q) * 256))[c];
                acc[q] += w.x * h.x + w.y * h.y + w.z * h.z + w.w * h.w;
            }
        }
        float b = p.sb2[d];
#pragma unroll
        for (int q = 0; q < 4; q++) rB[(q0 + q) * 128 + d] = leaky(acc[q] + b);
    }
    __syncthreads();
    // Layer 3: [8,128] -> [8,64]. d = tid&63, 2 points per quarter.
    {
        int d = tid & 63, q0 = (tid >> 6) * 2;
        const float4* wr = (const float4*)(p.sw3 + d * 128);
        float acc[2] = {0.f, 0.f};
        for (int c = 0; c < 32; c++) {
            float4 w = wr[c];
#pragma unroll
            for (int q = 0; q < 2; q++) {
                float4 h = ((const float4*)(rB + (q0 + q) * 128))[c];
                acc[q] += w.x * h.x + w.y * h.y + w.z * h.z + w.w * h.w;
            }
        }
        float b = p.sb3[d];
#pragma unroll
        for (int q = 0; q < 2; q++) rA[(q0 + q) * 64 + d] = leaky(acc[q] + b);
    }
    __syncthreads();
    // Layer 4: [8,64] -> [8,32]. d = tid&31, q = tid>>5 (one point each).
    {
        int d = tid & 31, q = tid >> 5;
        const float4* wr = (const float4*)(p.sw4 + d * 64);
        float a0 = 0.f, a1 = 0.f;
#pragma unroll
        for (int c = 0; c < 16; c += 2) {
            float4 w0 = wr[c],     h0 = ((const float4*)(rA + q * 64))[c];
            float4 w1 = wr[c + 1], h1 = ((const float4*)(rA + q * 64))[c + 1];
            a0 += w0.x * h0.x + w0.y * h0.y + w0.z * h0.z + w0.w * h0.w;
            a1 += w1.x * h1.x + w1.y * h1.y + w1.z * h1.z + w1.w * h1.w;
        }
        rB[q * 32 + d] = leaky(a0 + a1 + p.sb4[d]);
    }
    __syncthreads();
    // Layer 5: [8,32] -> [8,1].
    if (tid < TPTS && (n0 + tid) < p.n) {
        float acc = p.sb5[0];
#pragma unroll
        for (int c = 0; c < 32; c++) acc += p.sw5[c] * rB[tid * 32 + c];
        p.out[n0 + tid] = acc;
    }
}

extern "C" void kernel_launch(void* const* d_in, const int* in_sizes, int n_in,
                              void* d_out, int out_size, void* d_ws, size_t ws_size,
                              hipStream_t stream) {
    Params p;
    p.points = (const float*)d_in[0];
    p.nidx   = (const int*)  d_in[1];
    p.pw1 = (const float*)d_in[2];  p.pb1 = (const float*)d_in[3];
    p.pw2 = (const float*)d_in[4];  p.pb2 = (const float*)d_in[5];
    p.pw3 = (const float*)d_in[6];  p.pb3 = (const float*)d_in[7];
    p.sw1 = (const float*)d_in[8];  p.sb1 = (const float*)d_in[9];
    p.sw2 = (const float*)d_in[10]; p.sb2 = (const float*)d_in[11];
    p.sw3 = (const float*)d_in[12]; p.sb3 = (const float*)d_in[13];
    p.sw4 = (const float*)d_in[14]; p.sb4 = (const float*)d_in[15];
    p.sw5 = (const float*)d_in[16]; p.sb5 = (const float*)d_in[17];
    p.out = (float*)d_out;
    p.n   = in_sizes[0] / 3;

    int blocks = (p.n + TPTS - 1) / TPTS;
    hipLaunchKernelGGL(msp_kernel, dim3(blocks), dim3(256), 0, stream, p);
}

// Round 2
// 502.184 us; speedup vs baseline: 20.7277x; 20.7277x over previous
//
#include <hip/hip_runtime.h>

// MultiScalePointNet — f16 MFMA version.
// P=32 points/block, neighbor-major rows (r = k*32 + p) so maxpool over
// neighbors = elementwise max of C-fragments in registers.
// MFMA 16x16x32 f16, fp32 accum. Weights pre-swizzled to fragment-major
// fp16 in d_ws by prep_kernel (B-frag load = dwordx4 at base+lane*16).
// L1 (2% FLOPs) in fp32 VALU; sw5 + final in fp32 VALU.

typedef _Float16 f16x8 __attribute__((ext_vector_type(8)));
typedef float f32x4 __attribute__((ext_vector_type(4)));

#define NPTS 100000
#define PPB 32            // points per block
#define KMAX 20

// d_ws layout (offsets in halves unless noted)
#define PW2OFF 0          // 3 scales x 16 frags
#define PW3OFF 24576      // 3 scales x 64 frags
#define SW1OFF 122880     // 384 frags (nt*24 + kk)
#define SW2OFF 319488     // 64 frags
#define SW3OFF 352256     // 16 frags
#define SW4OFF 360448     // 4 frags
#define NFRAGS 708
#define PW1PAD_BYTES 724992   // fp32 [3][64][4] (w0,w1,w2,bias)

__device__ __forceinline__ float leaky(float x) { return fmaxf(x, 0.2f * x); }

// ---------------- prep: swizzle weights to fragment-major fp16 ----------------
struct PrepRegion { const float* src; int inC; int Kk; int fEnd; int dstOff; };
struct PrepParams {
    PrepRegion r[10];
    const float* pw1; const float* pb1;
    float* pw1pad; _Float16* dst;
};

__global__ __launch_bounds__(256) void prep_kernel(PrepParams pp) {
    int gid = blockIdx.x * 256 + threadIdx.x;
    if (gid < NFRAGS * 64) {
        int f = gid >> 6, L = gid & 63;
        int ri = 0;
        while (f >= pp.r[ri].fEnd) ri++;
        int f0 = (ri == 0) ? 0 : pp.r[ri - 1].fEnd;
        const PrepRegion R = pp.r[ri];
        int fl = f - f0;
        int nt = fl / R.Kk, kk = fl - nt * R.Kk;
        int row = nt * 16 + (L & 15);
        int col = kk * 32 + (L >> 4) * 8;
        const float* s = R.src + row * R.inC + col;
        f16x8 v;
#pragma unroll
        for (int j = 0; j < 8; ++j) v[j] = (_Float16)s[j];
        *(f16x8*)(pp.dst + R.dstOff + fl * 512 + L * 8) = v;
    } else if (gid < NFRAGS * 64 + 192) {
        int t = gid - NFRAGS * 64;
        int i = t >> 6, fd = t & 63;
        float4 w;
        w.x = pp.pw1[i * 192 + fd * 3 + 0];
        w.y = pp.pw1[i * 192 + fd * 3 + 1];
        w.z = pp.pw1[i * 192 + fd * 3 + 2];
        w.w = pp.pb1[i * 64 + fd];
        ((float4*)pp.pw1pad)[i * 64 + fd] = w;
    }
}

// ---------------- main kernel ----------------
struct MainParams {
    const float* points; const int* nidx;
    const float* pb2; const float* pb3;
    const float* sb1; const float* sb2; const float* sb3; const float* sb4;
    const float* sw5; const float* sb5;
    const _Float16* wsH; const float* pw1pad;
    float* out;
    int n;
};

// LDS (bytes): nb fp32 [640][4] @0 (10240) | pw1s fp32 [64][4] @10240 (1024)
// h1 fp16 [32][72] @11264 (4608) | h2 fp16 [32][136] @15872 (8704)
// xi fp16 [32][264] @24576 (16896)  => total 41472
#define LDS_BYTES 41472

__global__ __launch_bounds__(256, 2) void msp_mfma(MainParams p) {
    __shared__ __align__(16) unsigned char pool[LDS_BYTES];
    float*     nbf  = (float*)pool;                 // [640][4], later out4 [32][33] f32
    float*     pw1s = (float*)(pool + 10240);       // [64][4]
    _Float16*  h1   = (_Float16*)(pool + 11264);    // [32][72]
    _Float16*  h2   = (_Float16*)(pool + 15872);    // [32][136]
    _Float16*  xi   = (_Float16*)(pool + 24576);    // [32][264]

    const int tid  = threadIdx.x;
    const int wave = tid >> 6, lane = tid & 63;
    const int q = lane >> 4, m16 = lane & 15;
    const int n0 = blockIdx.x * PPB;

    // ---- gather: nb rows r = k*32 + p, padded to 4 floats (w=1 for bias dot4)
    for (int r = tid; r < PPB * KMAX; r += 256) {
        int pp_ = r & 31, k = r >> 5;
        int idx = p.nidx[(n0 + pp_) * KMAX + k];
        const float* npt = p.points + idx * 3;
        const float* cpt = p.points + (n0 + pp_) * 3;
        float4 v;
        v.x = npt[0] - cpt[0];
        v.y = npt[1] - cpt[1];
        v.z = npt[2] - cpt[2];
        v.w = 1.0f;
        ((float4*)nbf)[r] = v;
    }

    f32x4 accC[2][4];   // persistent sw1 accumulators [m-tile][n-sub]
#pragma unroll
    for (int mt = 0; mt < 2; ++mt)
#pragma unroll
        for (int t = 0; t < 4; ++t) accC[mt][t] = (f32x4){0.f, 0.f, 0.f, 0.f};

    __syncthreads();

    const int SS[3] = {5, 10, 20};
    for (int i = 0; i < 3; ++i) {
        const int S = SS[i];
        if (tid < 64)
            ((float4*)pw1s)[tid] = ((const float4*)p.pw1pad)[i * 64 + tid];

        // per-scale weight fragments in registers
        f16x8 W2f[2][2], W3f[4][4];
#pragma unroll
        for (int t2 = 0; t2 < 2; ++t2)
#pragma unroll
            for (int kk = 0; kk < 2; ++kk)
                W2f[t2][kk] = *(const f16x8*)(p.wsH + PW2OFF +
                    (i * 16 + (2 * wave + t2) * 2 + kk) * 512 + lane * 8);
#pragma unroll
        for (int t3 = 0; t3 < 4; ++t3)
#pragma unroll
            for (int kk = 0; kk < 4; ++kk)
                W3f[t3][kk] = *(const f16x8*)(p.wsH + PW3OFF +
                    (i * 64 + (4 * wave + t3) * 4 + kk) * 512 + lane * 8);

        float b2v[2], b3v[4];
#pragma unroll
        for (int t2 = 0; t2 < 2; ++t2) b2v[t2] = p.pb2[i * 128 + (2 * wave + t2) * 16 + m16];
#pragma unroll
        for (int t3 = 0; t3 < 4; ++t3) b3v[t3] = p.pb3[i * 256 + (4 * wave + t3) * 16 + m16];

        f32x4 maxC[2][4];
#pragma unroll
        for (int mt = 0; mt < 2; ++mt)
#pragma unroll
            for (int t3 = 0; t3 < 4; ++t3)
                maxC[mt][t3] = (f32x4){-3.0e38f, -3.0e38f, -3.0e38f, -3.0e38f};

        __syncthreads();

        for (int k = 0; k < S; ++k) {
            // ---- (a) L1: nb[k*32 + row] -> h1[32][64] fp16 (fp32 VALU)
            {
                int row = tid & 31, g = tid >> 5;   // g uniform-ish per wave half
                float4 nv = ((const float4*)nbf)[k * 32 + row];
                f16x8 hv;
#pragma unroll
                for (int j = 0; j < 8; ++j) {
                    float4 w = ((const float4*)pw1s)[g * 8 + j];
                    float v = fmaf(nv.x, w.x, fmaf(nv.y, w.y, fmaf(nv.z, w.z, w.w)));
                    hv[j] = (_Float16)leaky(v);
                }
                *(f16x8*)(h1 + row * 72 + g * 8) = hv;
            }
            __syncthreads();

            // ---- (b) L2: [32,64] x [64,128] -> h2 fp16 (bias+leaky)
#pragma unroll
            for (int mt = 0; mt < 2; ++mt) {
                const _Float16* ar = h1 + (mt * 16 + m16) * 72 + q * 8;
                f16x8 a0 = *(const f16x8*)(ar);
                f16x8 a1 = *(const f16x8*)(ar + 32);
                f32x4 acc[2];
#pragma unroll
                for (int t2 = 0; t2 < 2; ++t2) {
                    acc[t2] = __builtin_amdgcn_mfma_f32_16x16x32_f16(a0, W2f[t2][0],
                              (f32x4){0.f, 0.f, 0.f, 0.f}, 0, 0, 0);
                }
#pragma unroll
                for (int t2 = 0; t2 < 2; ++t2)
                    acc[t2] = __builtin_amdgcn_mfma_f32_16x16x32_f16(a1, W2f[t2][1], acc[t2], 0, 0, 0);
#pragma unroll
                for (int t2 = 0; t2 < 2; ++t2) {
                    int colb = (2 * wave + t2) * 16 + m16;
#pragma unroll
                    for (int r = 0; r < 4; ++r) {
                        float v = leaky(acc[t2][r] + b2v[t2]);
                        h2[(mt * 16 + q * 4 + r) * 136 + colb] = (_Float16)v;
                    }
                }
            }
            __syncthreads();

            // ---- (c) L3: [32,128] x [128,256] -> elementwise max into maxC
#pragma unroll
            for (int mt = 0; mt < 2; ++mt) {
                const _Float16* ar = h2 + (mt * 16 + m16) * 136;
                f16x8 a[4];
#pragma unroll
                for (int kk = 0; kk < 4; ++kk)
                    a[kk] = *(const f16x8*)(ar + kk * 32 + q * 8);
                f32x4 acc[4];
#pragma unroll
                for (int t3 = 0; t3 < 4; ++t3)
                    acc[t3] = __builtin_amdgcn_mfma_f32_16x16x32_f16(a[0], W3f[t3][0],
                              (f32x4){0.f, 0.f, 0.f, 0.f}, 0, 0, 0);
#pragma unroll
                for (int kk = 1; kk < 4; ++kk)
#pragma unroll
                    for (int t3 = 0; t3 < 4; ++t3)
                        acc[t3] = __builtin_amdgcn_mfma_f32_16x16x32_f16(a[kk], W3f[t3][kk], acc[t3], 0, 0, 0);
#pragma unroll
                for (int t3 = 0; t3 < 4; ++t3)
#pragma unroll
                    for (int r = 0; r < 4; ++r)
                        maxC[mt][t3][r] = fmaxf(maxC[mt][t3][r], acc[t3][r]);
            }
            // no barrier: next (a) writes h1 only; h2 rewrite is after next barrier
        }

        // ---- xi = maxC + pb3  -> LDS fp16 [32][264] (scale slice)
#pragma unroll
        for (int mt = 0; mt < 2; ++mt)
#pragma unroll
            for (int t3 = 0; t3 < 4; ++t3) {
                int col = (4 * wave + t3) * 16 + m16;
#pragma unroll
                for (int r = 0; r < 4; ++r)
                    xi[(mt * 16 + q * 4 + r) * 264 + col] = (_Float16)(maxC[mt][t3][r] + b3v[t3]);
            }
        __syncthreads();

        // ---- sw1 partial: xi [32,256] x sw1-slice -> accC (+=)
#pragma unroll
        for (int mt = 0; mt < 2; ++mt) {
            const _Float16* ar = xi + (mt * 16 + m16) * 264;
            f16x8 a[8];
#pragma unroll
            for (int kk = 0; kk < 8; ++kk)
                a[kk] = *(const f16x8*)(ar + kk * 32 + q * 8);
#pragma unroll
            for (int kk = 0; kk < 8; ++kk)
#pragma unroll
                for (int t = 0; t < 4; ++t) {
                    int nt = 4 * wave + t;
                    f16x8 b = *(const f16x8*)(p.wsH + SW1OFF +
                        (nt * 24 + i * 8 + kk) * 512 + lane * 8);
                    accC[mt][t] = __builtin_amdgcn_mfma_f32_16x16x32_f16(a[kk], b, accC[mt][t], 0, 0, 0);
                }
        }
        __syncthreads();
    }

    // ---- sw1 epilogue: leaky(accC + sb1) -> xi
#pragma unroll
    for (int mt = 0; mt < 2; ++mt)
#pragma unroll
        for (int t = 0; t < 4; ++t) {
            int col = (4 * wave + t) * 16 + m16;
            float b = p.sb1[col];
#pragma unroll
            for (int r = 0; r < 4; ++r)
                xi[(mt * 16 + q * 4 + r) * 264 + col] = (_Float16)leaky(accC[mt][t][r] + b);
        }
    __syncthreads();

    // ---- sw2: [32,256] x [256,128] -> h2
#pragma unroll
    for (int mt = 0; mt < 2; ++mt) {
        const _Float16* ar = xi + (mt * 16 + m16) * 264;
        f16x8 a[8];
#pragma unroll
        for (int kk = 0; kk < 8; ++kk)
            a[kk] = *(const f16x8*)(ar + kk * 32 + q * 8);
        f32x4 acc[2];
        acc[0] = acc[1] = (f32x4){0.f, 0.f, 0.f, 0.f};
#pragma unroll
        for (int kk = 0; kk < 8; ++kk)
#pragma unroll
            for (int t2 = 0; t2 < 2; ++t2) {
                int nt = 2 * wave + t2;
                f16x8 b = *(const f16x8*)(p.wsH + SW2OFF + (nt * 8 + kk) * 512 + lane * 8);
                acc[t2] = __builtin_amdgcn_mfma_f32_16x16x32_f16(a[kk], b, acc[t2], 0, 0, 0);
            }
#pragma unroll
        for (int t2 = 0; t2 < 2; ++t2) {
            int col = (2 * wave + t2) * 16 + m16;
            float b = p.sb2[col];
#pragma unroll
            for (int r = 0; r < 4; ++r)
                h2[(mt * 16 + q * 4 + r) * 136 + col] = (_Float16)leaky(acc[t2][r] + b);
        }
    }
    __syncthreads();

    // ---- sw3: [32,128] x [128,64] -> h1 (nt = wave)
    {
        f16x8 a[2][4];
#pragma unroll
        for (int mt = 0; mt < 2; ++mt) {
            const _Float16* ar = h2 + (mt * 16 + m16) * 136;
#pragma unroll
            for (int kk = 0; kk < 4; ++kk)
                a[mt][kk] = *(const f16x8*)(ar + kk * 32 + q * 8);
        }
        f32x4 acc[2];
        acc[0] = acc[1] = (f32x4){0.f, 0.f, 0.f, 0.f};
#pragma unroll
        for (int kk = 0; kk < 4; ++kk) {
            f16x8 b = *(const f16x8*)(p.wsH + SW3OFF + (wave * 4 + kk) * 512 + lane * 8);
#pragma unroll
            for (int mt = 0; mt < 2; ++mt)
                acc[mt] = __builtin_amdgcn_mfma_f32_16x16x32_f16(a[mt][kk], b, acc[mt], 0, 0, 0);
        }
        int col = wave * 16 + m16;
        float bb = p.sb3[col];
#pragma unroll
        for (int mt = 0; mt < 2; ++mt)
#pragma unroll
            for (int r = 0; r < 4; ++r)
                h1[(mt * 16 + q * 4 + r) * 72 + col] = (_Float16)leaky(acc[mt][r] + bb);
    }
    __syncthreads();

    // ---- sw4: [32,64] x [64,32] -> out4 f32 in nbf[32][33]  (waves 0,1)
    if (wave < 2) {
#pragma unroll
        for (int mt = 0; mt < 2; ++mt) {
            const _Float16* ar = h1 + (mt * 16 + m16) * 72;
            f16x8 a0 = *(const f16x8*)(ar + q * 8);
            f16x8 a1 = *(const f16x8*)(ar + 32 + q * 8);
            f32x4 acc = __builtin_amdgcn_mfma_f32_16x16x32_f16(a0,
                *(const f16x8*)(p.wsH + SW4OFF + (wave * 2 + 0) * 512 + lane * 8),
                (f32x4){0.f, 0.f, 0.f, 0.f}, 0, 0, 0);
            acc = __builtin_amdgcn_mfma_f32_16x16x32_f16(a1,
                *(const f16x8*)(p.wsH + SW4OFF + (wave * 2 + 1) * 512 + lane * 8),
                acc, 0, 0, 0);
            int col = wave * 16 + m16;
            float b = p.sb4[col];
#pragma unroll
            for (int r = 0; r < 4; ++r)
                nbf[(mt * 16 + q * 4 + r) * 33 + col] = leaky(acc[r] + b);
        }
    }
    __syncthreads();

    // ---- sw5: [32,32] x [32,1] -> out
    if (tid < PPB) {
        float acc = p.sb5[0];
#pragma unroll
        for (int c = 0; c < 32; ++c)
            acc = fmaf(nbf[tid * 33 + c], p.sw5[c], acc);
        p.out[n0 + tid] = acc;
    }
}

// ---------------- launch ----------------
extern "C" void kernel_launch(void* const* d_in, const int* in_sizes, int n_in,
                              void* d_out, int out_size, void* d_ws, size_t ws_size,
                              hipStream_t stream) {
    const float* points = (const float*)d_in[0];
    const int*   nidx   = (const int*)d_in[1];
    const float* pw1 = (const float*)d_in[2];  const float* pb1 = (const float*)d_in[3];
    const float* pw2 = (const float*)d_in[4];  const float* pb2 = (const float*)d_in[5];
    const float* pw3 = (const float*)d_in[6];  const float* pb3 = (const float*)d_in[7];
    const float* sw1 = (const float*)d_in[8];  const float* sb1 = (const float*)d_in[9];
    const float* sw2 = (const float*)d_in[10]; const float* sb2 = (const float*)d_in[11];
    const float* sw3 = (const float*)d_in[12]; const float* sb3 = (const float*)d_in[13];
    const float* sw4 = (const float*)d_in[14]; const float* sb4 = (const float*)d_in[15];
    const float* sw5 = (const float*)d_in[16]; const float* sb5 = (const float*)d_in[17];

    _Float16* wsH = (_Float16*)d_ws;
    float* pw1pad = (float*)((char*)d_ws + PW1PAD_BYTES);

    PrepParams pp;
    // pw2: 3 scales, [128][64], 16 frags each
    for (int i = 0; i < 3; ++i)
        pp.r[i] = { pw2 + i * 8192, 64, 2, 16 * (i + 1), PW2OFF + i * 8192 };
    // pw3: 3 scales, [256][128], 64 frags each
    for (int i = 0; i < 3; ++i)
        pp.r[3 + i] = { pw3 + i * 32768, 128, 4, 48 + 64 * (i + 1), PW3OFF + i * 32768 };
    pp.r[6] = { sw1, 768, 24, 624, SW1OFF };   // [256][768], 384 frags
    pp.r[7] = { sw2, 256, 8, 688, SW2OFF };    // [128][256], 64 frags
    pp.r[8] = { sw3, 128, 4, 704, SW3OFF };    // [64][128], 16 frags
    pp.r[9] = { sw4, 64, 2, 708, SW4OFF };     // [32][64], 4 frags
    pp.pw1 = pw1; pp.pb1 = pb1;
    pp.pw1pad = pw1pad; pp.dst = wsH;

    int prep_threads = NFRAGS * 64 + 192;
    hipLaunchKernelGGL(prep_kernel, dim3((prep_threads + 255) / 256), dim3(256), 0, stream, pp);

    MainParams mp;
    mp.points = points; mp.nidx = nidx;
    mp.pb2 = pb2; mp.pb3 = pb3;
    mp.sb1 = sb1; mp.sb2 = sb2; mp.sb3 = sb3; mp.sb4 = sb4;
    mp.sw5 = sw5; mp.sb5 = sb5;
    mp.wsH = wsH; mp.pw1pad = pw1pad;
    mp.out = (float*)d_out;
    mp.n = in_sizes[0] / 3;

    int blocks = mp.n / PPB;   // N=100000 -> 3125 exactly
    hipLaunchKernelGGL(msp_mfma, dim3(blocks), dim3(256), 0, stream, mp);
}